// Round 11
// baseline (251.872 us; speedup 1.0000x reference)
//
#include <hip/hip_runtime.h>

// G=64 graphs, P=1024 nodes/graph, D=64 feat, K=6 knn. N=65536.
// fp32 in/out; KNN via f16 MFMA + med3 top-6; pre_nn via f16 MFMA;
// all 4 conv layers fused in one LDS-resident kernel (h never leaves LDS).

typedef float4 f4;
typedef unsigned short ushort;
typedef unsigned int uint;
typedef _Float16 f16;
typedef _Float16 f16x8 __attribute__((ext_vector_type(8)));
typedef float f32x16 __attribute__((ext_vector_type(16)));

#define Z16 {0.f,0.f,0.f,0.f,0.f,0.f,0.f,0.f,0.f,0.f,0.f,0.f,0.f,0.f,0.f,0.f}

union HU { f16 h; ushort u; };
__device__ __forceinline__ ushort f2h_u(float f) { HU x; x.h = (f16)f; return x.u; }
__device__ __forceinline__ f16 u2h(ushort u) { HU x; x.u = u; return x.h; }

__device__ __forceinline__ uint med3u(uint a, uint b, uint c) {
  uint d;
  asm("v_med3_u32 %0, %1, %2, %3" : "=v"(d) : "v"(a), "v"(b), "v"(c));
  return d;
}

// 6-op insert of x into descending sorted m0>=...>=m5
#define INSM(x) do { \
  m5 = med3u((x), m4, m5); \
  m4 = med3u((x), m3, m4); \
  m3 = med3u((x), m2, m3); \
  m2 = med3u((x), m1, m2); \
  m1 = med3u((x), m0, m1); \
  m0 = max(m0, (x)); \
} while (0)

// ---- weight prep: W1,W2,conv_W[0..3] -> f16 transposed [n][k] ------------
__global__ void kwprep(const float* __restrict__ W1, const float* __restrict__ W2,
                       const float* __restrict__ convW, ushort* __restrict__ wt) {
  const int m = blockIdx.x;
  const float* src = (m == 0) ? W1 : (m == 1) ? W2 : convW + (m - 2) * 4096;
  ushort* dst = wt + m * 4096;
  for (int i = threadIdx.x; i < 4096; i += 256) {
    int k = i >> 6, n = i & 63;
    dst[n * 64 + k] = f2h_u(src[i]);
  }
}

// ---- KNN: f16 MFMA + packed-key med3 top-6 (unchanged from round 10) -----
__global__ __launch_bounds__(256, 4) void kknn(const ushort* __restrict__ xf16,
                                               const uint* __restrict__ sq2,
                                               int* __restrict__ nbr) {
  __shared__ uint skey[4][32][6];
  const int tid = threadIdx.x;
  const int lane = tid & 63;
  const int w = tid >> 6;
  const int q = lane & 31;
  const int h = lane >> 5;
  const int g = blockIdx.x >> 5;
  const int qtile = blockIdx.x & 31;
  const int gbase = g << 10;
  const int qloc = qtile * 32 + q;
  const int qglob = gbase + qloc;

  f16x8 Q0, Q1, Q2, Q3;
  {
    const ushort* qp = xf16 + (size_t)qglob * 64 + 8 * h;
    Q0 = *(const f16x8*)(qp);       Q1 = *(const f16x8*)(qp + 16);
    Q2 = *(const f16x8*)(qp + 32);  Q3 = *(const f16x8*)(qp + 48);
  }
  f16x8 Bsq = {(f16)0, (f16)0, (f16)0, (f16)0, (f16)0, (f16)0, (f16)0, (f16)0};
  if (h == 0) { Bsq[0] = (f16)1.0f; Bsq[1] = (f16)1.0f; }

  uint m0 = 0, m1 = 0, m2 = 0, m3 = 0, m4 = 0, m5 = 0;

  for (int cc = 0; cc < 8; ++cc) {
    const int cg = w * 8 + cc;
    const int cb = gbase + cg * 32;
    const ushort* cp = xf16 + (size_t)(cb + q) * 64 + 8 * h;
    f16x8 A0 = *(const f16x8*)(cp);       f16x8 A1 = *(const f16x8*)(cp + 16);
    f16x8 A2 = *(const f16x8*)(cp + 32);  f16x8 A3 = *(const f16x8*)(cp + 48);
    uint sv = sq2[cb + q];
    f16x8 Asq = {(f16)0, (f16)0, (f16)0, (f16)0, (f16)0, (f16)0, (f16)0, (f16)0};
    if (h == 0) { Asq[0] = u2h((ushort)(sv & 0xffffu)); Asq[1] = u2h((ushort)(sv >> 16)); }

    f32x16 acc = {1536.f,1536.f,1536.f,1536.f,1536.f,1536.f,1536.f,1536.f,
                  1536.f,1536.f,1536.f,1536.f,1536.f,1536.f,1536.f,1536.f};
    acc = __builtin_amdgcn_mfma_f32_32x32x16_f16(A0, Q0, acc, 0, 0, 0);
    acc = __builtin_amdgcn_mfma_f32_32x32x16_f16(A1, Q1, acc, 0, 0, 0);
    acc = __builtin_amdgcn_mfma_f32_32x32x16_f16(A2, Q2, acc, 0, 0, 0);
    acc = __builtin_amdgcn_mfma_f32_32x32x16_f16(A3, Q3, acc, 0, 0, 0);
    acc = __builtin_amdgcn_mfma_f32_32x32x16_f16(Asq, Bsq, acc, 0, 0, 0);

    const int cl0 = cg * 32 + 4 * h;
    const uint kb = (uint)(1023 - cl0);
    if (cg == qtile) {
#pragma unroll
      for (int r = 0; r < 16; ++r) {
        const int pat = (r & 3) + 8 * (r >> 2);
        uint u = __float_as_uint(acc[r]);
        uint key = (((u << 9) & 0xFFFFFC00u) | kb) - (uint)pat;
        if (cl0 + pat == qloc) key = 0u;
        INSM(key);
      }
    } else {
#pragma unroll
      for (int r = 0; r < 16; ++r) {
        const int pat = (r & 3) + 8 * (r >> 2);
        uint u = __float_as_uint(acc[r]);
        uint key = (((u << 9) & 0xFFFFFC00u) | kb) - (uint)pat;
        INSM(key);
      }
    }
  }

  {
    uint p0 = (uint)__shfl_xor((int)m0, 32, 64);
    uint p1 = (uint)__shfl_xor((int)m1, 32, 64);
    uint p2 = (uint)__shfl_xor((int)m2, 32, 64);
    uint p3 = (uint)__shfl_xor((int)m3, 32, 64);
    uint p4 = (uint)__shfl_xor((int)m4, 32, 64);
    uint p5 = (uint)__shfl_xor((int)m5, 32, 64);
    INSM(p0); INSM(p1); INSM(p2); INSM(p3); INSM(p4); INSM(p5);
  }
  if (h == 0) {
    skey[w][q][0] = m0; skey[w][q][1] = m1; skey[w][q][2] = m2;
    skey[w][q][3] = m3; skey[w][q][4] = m4; skey[w][q][5] = m5;
  }
  __syncthreads();

  if (tid < 32) {
    uint m0 = skey[0][tid][0], m1 = skey[0][tid][1], m2 = skey[0][tid][2];
    uint m3 = skey[0][tid][3], m4 = skey[0][tid][4], m5 = skey[0][tid][5];
#pragma unroll
    for (int ww = 1; ww < 4; ++ww)
#pragma unroll
      for (int k = 0; k < 6; ++k)
        INSM(skey[ww][tid][k]);
    const int ob = (gbase + qtile * 32 + tid) * 6;
    nbr[ob + 0] = gbase + 1023 - (int)(m0 & 1023u);
    nbr[ob + 1] = gbase + 1023 - (int)(m1 & 1023u);
    nbr[ob + 2] = gbase + 1023 - (int)(m2 & 1023u);
    nbr[ob + 3] = gbase + 1023 - (int)(m3 & 1023u);
    nbr[ob + 4] = gbase + 1023 - (int)(m4 & 1023u);
    nbr[ob + 5] = gbase + 1023 - (int)(m5 & 1023u);
  }
}

// ---- pre_nn via f16 MFMA (unchanged from round 10) ------------------------
__global__ __launch_bounds__(256) void kpre(
    const float* __restrict__ x, const ushort* __restrict__ w1t,
    const float* __restrict__ b1, const float* __restrict__ p1,
    const ushort* __restrict__ w2t, const float* __restrict__ b2,
    const float* __restrict__ p2, ushort* __restrict__ hout,
    float* __restrict__ gsumg, float* __restrict__ gsq,
    ushort* __restrict__ xf16, uint* __restrict__ sq2) {
  __shared__ ushort tile[4][32][72];
  __shared__ float ls[64], lq[64];
  const int tid = threadIdx.x, lane = tid & 63, w = tid >> 6;
  const int q = lane & 31, h = lane >> 5;
  const int rbase = blockIdx.x * 128 + w * 32;
  const int row = rbase + q;
  const int g = blockIdx.x >> 3;
  if (tid < 64) { ls[tid] = 0.f; lq[tid] = 0.f; }
  __syncthreads();

  f16x8 Ax[4]; float ssq = 0.f;
  const float* xp = x + (size_t)row * 64 + 8 * h;
  ushort* xo = xf16 + (size_t)row * 64 + 8 * h;
#pragma unroll
  for (int ks = 0; ks < 4; ++ks) {
    f4 a = *(const f4*)(xp + 16 * ks);
    f4 b = *(const f4*)(xp + 16 * ks + 4);
    f16x8 f;
    f[0] = (f16)a.x; f[1] = (f16)a.y; f[2] = (f16)a.z; f[3] = (f16)a.w;
    f[4] = (f16)b.x; f[5] = (f16)b.y; f[6] = (f16)b.z; f[7] = (f16)b.w;
    Ax[ks] = f;
    *(f16x8*)(xo + 16 * ks) = f;
    ssq += a.x*a.x + a.y*a.y + a.z*a.z + a.w*a.w + b.x*b.x + b.y*b.y + b.z*b.z + b.w*b.w;
  }
  ssq += __shfl_xor(ssq, 32, 64);
  if (h == 0) {
    float mm = -0.5f * ssq;
    ushort u1 = f2h_u(mm); HU t1; t1.u = u1;
    ushort u2 = f2h_u(mm - (float)t1.h);
    sq2[row] = (uint)u1 | ((uint)u2 << 16);
  }

  f32x16 c0 = Z16, c1 = Z16;
#pragma unroll
  for (int ks = 0; ks < 4; ++ks) {
    f16x8 B0 = *(const f16x8*)(w1t + q * 64 + 16 * ks + 8 * h);
    f16x8 B1 = *(const f16x8*)(w1t + (q + 32) * 64 + 16 * ks + 8 * h);
    c0 = __builtin_amdgcn_mfma_f32_32x32x16_f16(Ax[ks], B0, c0, 0, 0, 0);
    c1 = __builtin_amdgcn_mfma_f32_32x32x16_f16(Ax[ks], B1, c1, 0, 0, 0);
  }
  {
    const float bb0 = b1[q], aa0 = p1[q], bb1 = b1[q + 32], aa1 = p1[q + 32];
#pragma unroll
    for (int r = 0; r < 16; ++r) {
      const int nd = (r & 3) + 8 * (r >> 2) + 4 * h;
      float v0 = c0[r] + bb0; v0 = v0 >= 0.f ? v0 : aa0 * v0;
      float v1 = c1[r] + bb1; v1 = v1 >= 0.f ? v1 : aa1 * v1;
      tile[w][nd][q] = f2h_u(v0);
      tile[w][nd][q + 32] = f2h_u(v1);
    }
  }
  f16x8 Ah[4];
#pragma unroll
  for (int ks = 0; ks < 4; ++ks)
    Ah[ks] = *(const f16x8*)&tile[w][q][16 * ks + 8 * h];

  f32x16 d0 = Z16, d1 = Z16;
#pragma unroll
  for (int ks = 0; ks < 4; ++ks) {
    f16x8 B0 = *(const f16x8*)(w2t + q * 64 + 16 * ks + 8 * h);
    f16x8 B1 = *(const f16x8*)(w2t + (q + 32) * 64 + 16 * ks + 8 * h);
    d0 = __builtin_amdgcn_mfma_f32_32x32x16_f16(Ah[ks], B0, d0, 0, 0, 0);
    d1 = __builtin_amdgcn_mfma_f32_32x32x16_f16(Ah[ks], B1, d1, 0, 0, 0);
  }
  {
    const float bb0 = b2[q], aa0 = p2[q], bb1 = b2[q + 32], aa1 = p2[q + 32];
    float s0 = 0.f, q0 = 0.f, s1 = 0.f, q1 = 0.f;
#pragma unroll
    for (int r = 0; r < 16; ++r) {
      const int nd = (r & 3) + 8 * (r >> 2) + 4 * h;
      float v0 = d0[r] + bb0; v0 = v0 >= 0.f ? v0 : aa0 * v0;
      float v1 = d1[r] + bb1; v1 = v1 >= 0.f ? v1 : aa1 * v1;
      ushort u0 = f2h_u(v0), u1 = f2h_u(v1);
      HU t0, t1; t0.u = u0; t1.u = u1;
      float r0 = (float)t0.h, r1 = (float)t1.h;
      s0 += r0; q0 += r0 * r0; s1 += r1; q1 += r1 * r1;
      tile[w][nd][q] = u0;
      tile[w][nd][q + 32] = u1;
    }
    s0 += __shfl_xor(s0, 32, 64); q0 += __shfl_xor(q0, 32, 64);
    s1 += __shfl_xor(s1, 32, 64); q1 += __shfl_xor(q1, 32, 64);
    if (h == 0) {
      atomicAdd(&ls[q], s0); atomicAdd(&lq[q], q0);
      atomicAdd(&ls[q + 32], s1); atomicAdd(&lq[q + 32], q1);
    }
  }
  ushort* ho = hout + (size_t)row * 64 + 8 * h;
#pragma unroll
  for (int ks = 0; ks < 4; ++ks) {
    f16x8 v = *(const f16x8*)&tile[w][q][16 * ks + 8 * h];
    *(f16x8*)(ho + 16 * ks) = v;
  }
  __syncthreads();
  if (tid < 64) {
    atomicAdd(&gsumg[g * 64 + tid], ls[tid]);
    atomicAdd(&gsq[tid], lq[tid]);
  }
}

// ---- finalize BN: scale/shift + analytic stage-0 pool ---------------------
__global__ void kfin(const float* __restrict__ gsumg, const float* __restrict__ gsq,
                     const float* __restrict__ gamma, const float* __restrict__ beta,
                     float* __restrict__ scale, float* __restrict__ shift,
                     float* __restrict__ pooled) {
  const int g = blockIdx.x, f = threadIdx.x;
  float s = 0.f;
  for (int g2 = 0; g2 < 64; ++g2) s += gsumg[g2 * 64 + f];
  float mu = s * (1.f / 65536.f);
  float var = gsq[f] * (1.f / 65536.f) - mu * mu;
  float sc = gamma[f] * rsqrtf(var + 1e-5f);
  float sh = beta[f] - mu * sc;
  pooled[g * 320 + f] = sc * gsumg[g * 64 + f] + 1024.f * sh;
  if (g == 0) { scale[f] = sc; shift[f] = sh; }
}

// ---- fused 4-layer conv: one block per graph, h resident in LDS ----------
// Load h+BN once -> 4x {gather(LDS) -> MFMA -> residual/PReLU -> pool}.
__global__ __launch_bounds__(1024, 4) void kconv4(
    const ushort* __restrict__ hIn, const int* __restrict__ nbr,
    const ushort* __restrict__ wt, const float* __restrict__ cb,
    const float* __restrict__ act, const float* __restrict__ scale,
    const float* __restrict__ shift, float* __restrict__ pooled) {
  __shared__ ushort hl[1024][72];      // stride 72 f16 = 144B (16B-aligned rows)
  __shared__ float pool[64];
  const int tid = threadIdx.x, lane = tid & 63, w = tid >> 6;
  const int q = lane & 31, h = lane >> 5;
  const int g = blockIdx.x;
  const size_t gb = (size_t)g * 65536;

  {  // global -> LDS with BN applied (8 threads/row, 8 passes, coalesced)
    const int seg = tid & 7, r0 = tid >> 3;
    const f4 sa = *(const f4*)(scale + seg * 8);
    const f4 sb = *(const f4*)(scale + seg * 8 + 4);
    const f4 ha = *(const f4*)(shift + seg * 8);
    const f4 hb = *(const f4*)(shift + seg * 8 + 4);
#pragma unroll
    for (int p = 0; p < 8; ++p) {
      const int row = r0 + p * 128;
      f16x8 v = *(const f16x8*)(hIn + gb + (size_t)row * 64 + seg * 8);
      f16x8 o;
      o[0] = (f16)((float)v[0] * sa.x + ha.x);
      o[1] = (f16)((float)v[1] * sa.y + ha.y);
      o[2] = (f16)((float)v[2] * sa.z + ha.z);
      o[3] = (f16)((float)v[3] * sa.w + ha.w);
      o[4] = (f16)((float)v[4] * sb.x + hb.x);
      o[5] = (f16)((float)v[5] * sb.y + hb.y);
      o[6] = (f16)((float)v[6] * sb.z + hb.z);
      o[7] = (f16)((float)v[7] * sb.w + hb.w);
      *(f16x8*)&hl[row][seg * 8] = o;
    }
  }
  if (tid < 64) pool[tid] = 0.f;

  const int nb0 = w * 64, nb1 = nb0 + 32;   // two 32-node tiles per wave
  int n0[6], n1[6];
  {
    const int* p0 = nbr + (size_t)(g * 1024 + nb0 + q) * 6;
    const int* p1 = p0 + 32 * 6;
#pragma unroll
    for (int k = 0; k < 6; ++k) { n0[k] = p0[k] & 1023; n1[k] = p1[k] & 1023; }
  }
  __syncthreads();

  for (int l = 0; l < 4; ++l) {
    const ushort* wl = wt + (2 + l) * 4096;
    const float bb0 = 6.f * cb[l * 64 + q], bb1 = 6.f * cb[l * 64 + q + 32];
    const float av0 = act[q], av1 = act[q + 32];
    uint o0[2][8], o1[2][8];
#pragma unroll
    for (int t = 0; t < 2; ++t) {
      const int nb = t ? nb1 : nb0;
      const int* nn = t ? n1 : n0;
      f32x16 c0 = Z16, c1 = Z16;
#pragma unroll
      for (int ks = 0; ks < 4; ++ks) {
        const int off = 16 * ks + 8 * h;
        float s0=0.f,s1=0.f,s2=0.f,s3=0.f,s4=0.f,s5=0.f,s6=0.f,s7=0.f;
#pragma unroll
        for (int k = 0; k < 6; ++k) {
          f16x8 v = *(const f16x8*)&hl[nn[k]][off];
          s0 += (float)v[0]; s1 += (float)v[1]; s2 += (float)v[2]; s3 += (float)v[3];
          s4 += (float)v[4]; s5 += (float)v[5]; s6 += (float)v[6]; s7 += (float)v[7];
        }
        f16x8 Af;
        Af[0]=(f16)s0; Af[1]=(f16)s1; Af[2]=(f16)s2; Af[3]=(f16)s3;
        Af[4]=(f16)s4; Af[5]=(f16)s5; Af[6]=(f16)s6; Af[7]=(f16)s7;
        f16x8 B0 = *(const f16x8*)(wl + q * 64 + off);
        f16x8 B1 = *(const f16x8*)(wl + (q + 32) * 64 + off);
        c0 = __builtin_amdgcn_mfma_f32_32x32x16_f16(Af, B0, c0, 0, 0, 0);
        c1 = __builtin_amdgcn_mfma_f32_32x32x16_f16(Af, B1, c1, 0, 0, 0);
      }
      float p0s = 0.f, p1s = 0.f;
#pragma unroll
      for (int r = 0; r < 16; ++r) {
        const int nd = nb + (r & 3) + 8 * (r >> 2) + 4 * h;
        float r0 = (float)u2h(hl[nd][q]);
        float r1 = (float)u2h(hl[nd][q + 32]);
        float v0 = c0[r] + bb0 + r0; v0 = v0 >= 0.f ? v0 : av0 * v0;
        float v1 = c1[r] + bb1 + r1; v1 = v1 >= 0.f ? v1 : av1 * v1;
        p0s += v0; p1s += v1;
        uint u0 = (uint)f2h_u(v0), u1 = (uint)f2h_u(v1);
        if (r & 1) { o0[t][r >> 1] |= u0 << 16; o1[t][r >> 1] |= u1 << 16; }
        else       { o0[t][r >> 1] = u0;        o1[t][r >> 1] = u1; }
      }
      atomicAdd(&pool[q], p0s);
      atomicAdd(&pool[q + 32], p1s);
    }
    __syncthreads();                      // all reads of old h complete
#pragma unroll
    for (int t = 0; t < 2; ++t) {
      const int nb = t ? nb1 : nb0;
#pragma unroll
      for (int r = 0; r < 16; ++r) {
        const int nd = nb + (r & 3) + 8 * (r >> 2) + 4 * h;
        hl[nd][q]      = (ushort)(o0[t][r >> 1] >> (16 * (r & 1)));
        hl[nd][q + 32] = (ushort)(o1[t][r >> 1] >> (16 * (r & 1)));
      }
    }
    if (tid < 64) {
      atomicAdd(&pooled[g * 320 + 64 * (l + 1) + tid], pool[tid]);
      pool[tid] = 0.f;
    }
    __syncthreads();                      // new h visible; pool rezeroed
  }
}

// ---------------- FFN head: one block per graph ----------------------------
__global__ __launch_bounds__(256) void kffn(const float* __restrict__ pooled,
    const float* __restrict__ W1, const float* __restrict__ b1,
    const float* __restrict__ W2, const float* __restrict__ b2,
    float* __restrict__ out) {
  __shared__ float pg[320];
  __shared__ float z1[320];
  __shared__ float red[4];
  const int g = blockIdx.x, tid = threadIdx.x;
  for (int i = tid; i < 320; i += 256) pg[i] = pooled[g * 320 + i];
  __syncthreads();
  for (int o = tid; o < 320; o += 256) {
    float acc = b1[o];
    for (int d = 0; d < 320; ++d) acc += pg[d] * W1[d * 320 + o];
    z1[o] = acc >= 0.f ? acc : 0.01f * acc;
  }
  __syncthreads();
  float p = 0.f;
  for (int o = tid; o < 320; o += 256) p += z1[o] * W2[o];
#pragma unroll
  for (int m = 32; m; m >>= 1) p += __shfl_xor(p, m, 64);
  if ((tid & 63) == 0) red[tid >> 6] = p;
  __syncthreads();
  if (tid == 0) out[g] = red[0] + red[1] + red[2] + red[3] + b2[0];
}

extern "C" void kernel_launch(void* const* d_in, const int* in_sizes, int n_in,
                              void* d_out, int out_size, void* d_ws, size_t ws_size,
                              hipStream_t stream) {
  const float* x        = (const float*)d_in[0];
  const float* pre_W1   = (const float*)d_in[2];
  const float* pre_b1   = (const float*)d_in[3];
  const float* pre_a1   = (const float*)d_in[4];
  const float* pre_W2   = (const float*)d_in[5];
  const float* pre_b2   = (const float*)d_in[6];
  const float* pre_a2   = (const float*)d_in[7];
  const float* bn_gamma = (const float*)d_in[8];
  const float* bn_beta  = (const float*)d_in[9];
  const float* act_a    = (const float*)d_in[10];
  const float* conv_W   = (const float*)d_in[11];
  const float* conv_b   = (const float*)d_in[12];
  const float* ffn_W1   = (const float*)d_in[13];
  const float* ffn_b1   = (const float*)d_in[14];
  const float* ffn_W2   = (const float*)d_in[15];
  const float* ffn_b2   = (const float*)d_in[16];
  float* out = (float*)d_out;

  ushort* hA16 = (ushort*)d_ws;                     // N*64 f16 (8 MB)
  ushort* xf16 = hA16 + 4194304;                    // N*64 f16 (8 MB)
  uint*   sq2  = (uint*)(xf16 + 4194304);           // N
  int*    nbr  = (int*)(sq2 + 65536);               // N*6
  ushort* wt   = (ushort*)(nbr + 393216);           // 6*4096 f16 (48 KB)
  float* stats = (float*)(wt + 24576);
  float* gsq    = stats;                            // 64
  float* gsumg  = stats + 64;                       // 64*64
  float* scale  = stats + 64 + 4096;                // 64
  float* shift  = stats + 64 + 4096 + 64;           // 64
  float* pooled = stats + 64 + 4096 + 128;          // 64*320

  hipMemsetAsync(stats, 0, (64 + 4096 + 128 + 64 * 320) * sizeof(float), stream);

  kwprep<<<6, 256, 0, stream>>>(pre_W1, pre_W2, conv_W, wt);
  kpre  <<<512, 256, 0, stream>>>(x, wt, pre_b1, pre_a1, wt + 4096, pre_b2, pre_a2,
                                  hA16, gsumg, gsq, xf16, sq2);
  kknn  <<<2048, 256, 0, stream>>>(xf16, sq2, nbr);
  kfin  <<<64, 64, 0, stream>>>(gsumg, gsq, bn_gamma, bn_beta, scale, shift, pooled);
  kconv4<<<64, 1024, 0, stream>>>(hA16, nbr, wt, conv_b, act_a, scale, shift, pooled);
  kffn  <<<64, 256, 0, stream>>>(pooled, ffn_W1, ffn_b1, ffn_W2, ffn_b2, out);
}

// Round 12
// 241.215 us; speedup vs baseline: 1.0442x; 1.0442x over previous
//
#include <hip/hip_runtime.h>

// G=64 graphs, P=1024 nodes/graph, D=64 feat, K=6 knn. N=65536.
// fp32 in/out; KNN via f16 MFMA (software-pipelined) + med3 top-6;
// pre_nn/conv GEMMs via f16 MFMA; h buffers stored f16.

typedef float4 f4;
typedef unsigned short ushort;
typedef unsigned int uint;
typedef _Float16 f16;
typedef _Float16 f16x8 __attribute__((ext_vector_type(8)));
typedef float f32x16 __attribute__((ext_vector_type(16)));

#define Z16 {0.f,0.f,0.f,0.f,0.f,0.f,0.f,0.f,0.f,0.f,0.f,0.f,0.f,0.f,0.f,0.f}

union HU { f16 h; ushort u; };
__device__ __forceinline__ ushort f2h_u(float f) { HU x; x.h = (f16)f; return x.u; }
__device__ __forceinline__ f16 u2h(ushort u) { HU x; x.u = u; return x.h; }

__device__ __forceinline__ uint med3u(uint a, uint b, uint c) {
  uint d;
  asm("v_med3_u32 %0, %1, %2, %3" : "=v"(d) : "v"(a), "v"(b), "v"(c));
  return d;
}

// 6-op insert of x into descending sorted m0>=...>=m5
#define INSM(x) do { \
  m5 = med3u((x), m4, m5); \
  m4 = med3u((x), m3, m4); \
  m3 = med3u((x), m2, m3); \
  m2 = med3u((x), m1, m2); \
  m1 = med3u((x), m0, m1); \
  m0 = max(m0, (x)); \
} while (0)

// ---- weight prep: W1,W2,conv_W[0..3] -> f16 transposed [n][k] ------------
__global__ void kwprep(const float* __restrict__ W1, const float* __restrict__ W2,
                       const float* __restrict__ convW, ushort* __restrict__ wt) {
  const int m = blockIdx.x;
  const float* src = (m == 0) ? W1 : (m == 1) ? W2 : convW + (m - 2) * 4096;
  ushort* dst = wt + m * 4096;
  for (int i = threadIdx.x; i < 4096; i += 256) {
    int k = i >> 6, n = i & 63;
    dst[n * 64 + k] = f2h_u(src[i]);
  }
}

// ---- KNN: f16 MFMA + med3 top-6; chunk-pipelined (loads overlap select) --
__global__ __launch_bounds__(256, 4) void kknn(const ushort* __restrict__ xf16,
                                               const uint* __restrict__ sq2,
                                               int* __restrict__ nbr) {
  __shared__ uint skey[4][32][6];
  const int tid = threadIdx.x;
  const int lane = tid & 63;
  const int w = tid >> 6;
  const int q = lane & 31;
  const int h = lane >> 5;
  const int g = blockIdx.x >> 5;
  const int qtile = blockIdx.x & 31;
  const int gbase = g << 10;
  const int qloc = qtile * 32 + q;
  const int qglob = gbase + qloc;

  f16x8 Q0, Q1, Q2, Q3;
  {
    const ushort* qp = xf16 + (size_t)qglob * 64 + 8 * h;
    Q0 = *(const f16x8*)(qp);       Q1 = *(const f16x8*)(qp + 16);
    Q2 = *(const f16x8*)(qp + 32);  Q3 = *(const f16x8*)(qp + 48);
  }
  f16x8 Bsq = {(f16)0, (f16)0, (f16)0, (f16)0, (f16)0, (f16)0, (f16)0, (f16)0};
  if (h == 0) { Bsq[0] = (f16)1.0f; Bsq[1] = (f16)1.0f; }

  uint m0 = 0, m1 = 0, m2 = 0, m3 = 0, m4 = 0, m5 = 0;

  // preload chunk 0
  const int cg0 = w * 8;
  f16x8 A0, A1, A2, A3; uint sv;
  {
    const ushort* cp = xf16 + (size_t)(gbase + cg0 * 32 + q) * 64 + 8 * h;
    A0 = *(const f16x8*)(cp);       A1 = *(const f16x8*)(cp + 16);
    A2 = *(const f16x8*)(cp + 32);  A3 = *(const f16x8*)(cp + 48);
    sv = sq2[gbase + cg0 * 32 + q];
  }

#pragma unroll
  for (int cc = 0; cc < 8; ++cc) {
    const int cg = cg0 + cc;
    f16x8 Asq = {(f16)0, (f16)0, (f16)0, (f16)0, (f16)0, (f16)0, (f16)0, (f16)0};
    if (h == 0) { Asq[0] = u2h((ushort)(sv & 0xffffu)); Asq[1] = u2h((ushort)(sv >> 16)); }

    f32x16 acc = {1536.f,1536.f,1536.f,1536.f,1536.f,1536.f,1536.f,1536.f,
                  1536.f,1536.f,1536.f,1536.f,1536.f,1536.f,1536.f,1536.f};
    acc = __builtin_amdgcn_mfma_f32_32x32x16_f16(A0, Q0, acc, 0, 0, 0);
    acc = __builtin_amdgcn_mfma_f32_32x32x16_f16(A1, Q1, acc, 0, 0, 0);
    acc = __builtin_amdgcn_mfma_f32_32x32x16_f16(A2, Q2, acc, 0, 0, 0);
    acc = __builtin_amdgcn_mfma_f32_32x32x16_f16(A3, Q3, acc, 0, 0, 0);
    acc = __builtin_amdgcn_mfma_f32_32x32x16_f16(Asq, Bsq, acc, 0, 0, 0);

    // issue next chunk's loads; their latency hides under the select loop
    if (cc < 7) {
      const ushort* cp = xf16 + (size_t)(gbase + (cg + 1) * 32 + q) * 64 + 8 * h;
      A0 = *(const f16x8*)(cp);       A1 = *(const f16x8*)(cp + 16);
      A2 = *(const f16x8*)(cp + 32);  A3 = *(const f16x8*)(cp + 48);
      sv = sq2[gbase + (cg + 1) * 32 + q];
    }

    const int cl0 = cg * 32 + 4 * h;
    const uint kb = (uint)(1023 - cl0);
    if (cg == qtile) {
#pragma unroll
      for (int r = 0; r < 16; ++r) {
        const int pat = (r & 3) + 8 * (r >> 2);
        uint u = __float_as_uint(acc[r]);
        uint key = ((u << 9) & 0xFFFFFC00u) | (kb - (uint)pat);
        if (cl0 + pat == qloc) key = 0u;
        INSM(key);
      }
    } else {
#pragma unroll
      for (int r = 0; r < 16; ++r) {
        const int pat = (r & 3) + 8 * (r >> 2);
        uint u = __float_as_uint(acc[r]);
        uint key = ((u << 9) & 0xFFFFFC00u) | (kb - (uint)pat);
        INSM(key);
      }
    }
  }

  {
    uint p0 = (uint)__shfl_xor((int)m0, 32, 64);
    uint p1 = (uint)__shfl_xor((int)m1, 32, 64);
    uint p2 = (uint)__shfl_xor((int)m2, 32, 64);
    uint p3 = (uint)__shfl_xor((int)m3, 32, 64);
    uint p4 = (uint)__shfl_xor((int)m4, 32, 64);
    uint p5 = (uint)__shfl_xor((int)m5, 32, 64);
    INSM(p0); INSM(p1); INSM(p2); INSM(p3); INSM(p4); INSM(p5);
  }
  if (h == 0) {
    skey[w][q][0] = m0; skey[w][q][1] = m1; skey[w][q][2] = m2;
    skey[w][q][3] = m3; skey[w][q][4] = m4; skey[w][q][5] = m5;
  }
  __syncthreads();

  if (tid < 32) {
    uint m0 = skey[0][tid][0], m1 = skey[0][tid][1], m2 = skey[0][tid][2];
    uint m3 = skey[0][tid][3], m4 = skey[0][tid][4], m5 = skey[0][tid][5];
#pragma unroll
    for (int ww = 1; ww < 4; ++ww)
#pragma unroll
      for (int k = 0; k < 6; ++k)
        INSM(skey[ww][tid][k]);
    const int ob = (gbase + qtile * 32 + tid) * 6;
    nbr[ob + 0] = gbase + 1023 - (int)(m0 & 1023u);
    nbr[ob + 1] = gbase + 1023 - (int)(m1 & 1023u);
    nbr[ob + 2] = gbase + 1023 - (int)(m2 & 1023u);
    nbr[ob + 3] = gbase + 1023 - (int)(m3 & 1023u);
    nbr[ob + 4] = gbase + 1023 - (int)(m4 & 1023u);
    nbr[ob + 5] = gbase + 1023 - (int)(m5 & 1023u);
  }
}

// ---- pre_nn via f16 MFMA (round-10 version) -------------------------------
__global__ __launch_bounds__(256) void kpre(
    const float* __restrict__ x, const ushort* __restrict__ w1t,
    const float* __restrict__ b1, const float* __restrict__ p1,
    const ushort* __restrict__ w2t, const float* __restrict__ b2,
    const float* __restrict__ p2, ushort* __restrict__ hout,
    float* __restrict__ gsumg, float* __restrict__ gsq,
    ushort* __restrict__ xf16, uint* __restrict__ sq2) {
  __shared__ ushort tile[4][32][72];
  __shared__ float ls[64], lq[64];
  const int tid = threadIdx.x, lane = tid & 63, w = tid >> 6;
  const int q = lane & 31, h = lane >> 5;
  const int rbase = blockIdx.x * 128 + w * 32;
  const int row = rbase + q;
  const int g = blockIdx.x >> 3;
  if (tid < 64) { ls[tid] = 0.f; lq[tid] = 0.f; }
  __syncthreads();

  f16x8 Ax[4]; float ssq = 0.f;
  const float* xp = x + (size_t)row * 64 + 8 * h;
  ushort* xo = xf16 + (size_t)row * 64 + 8 * h;
#pragma unroll
  for (int ks = 0; ks < 4; ++ks) {
    f4 a = *(const f4*)(xp + 16 * ks);
    f4 b = *(const f4*)(xp + 16 * ks + 4);
    f16x8 f;
    f[0] = (f16)a.x; f[1] = (f16)a.y; f[2] = (f16)a.z; f[3] = (f16)a.w;
    f[4] = (f16)b.x; f[5] = (f16)b.y; f[6] = (f16)b.z; f[7] = (f16)b.w;
    Ax[ks] = f;
    *(f16x8*)(xo + 16 * ks) = f;
    ssq += a.x*a.x + a.y*a.y + a.z*a.z + a.w*a.w + b.x*b.x + b.y*b.y + b.z*b.z + b.w*b.w;
  }
  ssq += __shfl_xor(ssq, 32, 64);
  if (h == 0) {
    float mm = -0.5f * ssq;
    ushort u1 = f2h_u(mm); HU t1; t1.u = u1;
    ushort u2 = f2h_u(mm - (float)t1.h);
    sq2[row] = (uint)u1 | ((uint)u2 << 16);
  }

  f32x16 c0 = Z16, c1 = Z16;
#pragma unroll
  for (int ks = 0; ks < 4; ++ks) {
    f16x8 B0 = *(const f16x8*)(w1t + q * 64 + 16 * ks + 8 * h);
    f16x8 B1 = *(const f16x8*)(w1t + (q + 32) * 64 + 16 * ks + 8 * h);
    c0 = __builtin_amdgcn_mfma_f32_32x32x16_f16(Ax[ks], B0, c0, 0, 0, 0);
    c1 = __builtin_amdgcn_mfma_f32_32x32x16_f16(Ax[ks], B1, c1, 0, 0, 0);
  }
  {
    const float bb0 = b1[q], aa0 = p1[q], bb1 = b1[q + 32], aa1 = p1[q + 32];
#pragma unroll
    for (int r = 0; r < 16; ++r) {
      const int nd = (r & 3) + 8 * (r >> 2) + 4 * h;
      float v0 = c0[r] + bb0; v0 = v0 >= 0.f ? v0 : aa0 * v0;
      float v1 = c1[r] + bb1; v1 = v1 >= 0.f ? v1 : aa1 * v1;
      tile[w][nd][q] = f2h_u(v0);
      tile[w][nd][q + 32] = f2h_u(v1);
    }
  }
  f16x8 Ah[4];
#pragma unroll
  for (int ks = 0; ks < 4; ++ks)
    Ah[ks] = *(const f16x8*)&tile[w][q][16 * ks + 8 * h];

  f32x16 d0 = Z16, d1 = Z16;
#pragma unroll
  for (int ks = 0; ks < 4; ++ks) {
    f16x8 B0 = *(const f16x8*)(w2t + q * 64 + 16 * ks + 8 * h);
    f16x8 B1 = *(const f16x8*)(w2t + (q + 32) * 64 + 16 * ks + 8 * h);
    d0 = __builtin_amdgcn_mfma_f32_32x32x16_f16(Ah[ks], B0, d0, 0, 0, 0);
    d1 = __builtin_amdgcn_mfma_f32_32x32x16_f16(Ah[ks], B1, d1, 0, 0, 0);
  }
  {
    const float bb0 = b2[q], aa0 = p2[q], bb1 = b2[q + 32], aa1 = p2[q + 32];
    float s0 = 0.f, q0 = 0.f, s1 = 0.f, q1 = 0.f;
#pragma unroll
    for (int r = 0; r < 16; ++r) {
      const int nd = (r & 3) + 8 * (r >> 2) + 4 * h;
      float v0 = d0[r] + bb0; v0 = v0 >= 0.f ? v0 : aa0 * v0;
      float v1 = d1[r] + bb1; v1 = v1 >= 0.f ? v1 : aa1 * v1;
      ushort u0 = f2h_u(v0), u1 = f2h_u(v1);
      HU t0, t1; t0.u = u0; t1.u = u1;
      float r0 = (float)t0.h, r1 = (float)t1.h;
      s0 += r0; q0 += r0 * r0; s1 += r1; q1 += r1 * r1;
      tile[w][nd][q] = u0;
      tile[w][nd][q + 32] = u1;
    }
    s0 += __shfl_xor(s0, 32, 64); q0 += __shfl_xor(q0, 32, 64);
    s1 += __shfl_xor(s1, 32, 64); q1 += __shfl_xor(q1, 32, 64);
    if (h == 0) {
      atomicAdd(&ls[q], s0); atomicAdd(&lq[q], q0);
      atomicAdd(&ls[q + 32], s1); atomicAdd(&lq[q + 32], q1);
    }
  }
  ushort* ho = hout + (size_t)row * 64 + 8 * h;
#pragma unroll
  for (int ks = 0; ks < 4; ++ks) {
    f16x8 v = *(const f16x8*)&tile[w][q][16 * ks + 8 * h];
    *(f16x8*)(ho + 16 * ks) = v;
  }
  __syncthreads();
  if (tid < 64) {
    atomicAdd(&gsumg[g * 64 + tid], ls[tid]);
    atomicAdd(&gsq[tid], lq[tid]);
  }
}

// ---- finalize BN: scale/shift + analytic stage-0 pool ---------------------
__global__ void kfin(const float* __restrict__ gsumg, const float* __restrict__ gsq,
                     const float* __restrict__ gamma, const float* __restrict__ beta,
                     float* __restrict__ scale, float* __restrict__ shift,
                     float* __restrict__ pooled) {
  const int g = blockIdx.x, f = threadIdx.x;
  float s = 0.f;
  for (int g2 = 0; g2 < 64; ++g2) s += gsumg[g2 * 64 + f];
  float mu = s * (1.f / 65536.f);
  float var = gsq[f] * (1.f / 65536.f) - mu * mu;
  float sc = gamma[f] * rsqrtf(var + 1e-5f);
  float sh = beta[f] - mu * sc;
  pooled[g * 320 + f] = sc * gsumg[g * 64 + f] + 1024.f * sh;
  if (g == 0) { scale[f] = sc; shift[f] = sh; }
}

// ---- conv layer (f16): prefetched gather(+BN) -> MFMA -> epilogue ---------
template <int BN>
__global__ __launch_bounds__(256) void kconv(
    const ushort* __restrict__ hIn, ushort* __restrict__ hOut,
    const int* __restrict__ nbr, const ushort* __restrict__ wt,
    const float* __restrict__ bias, const float* __restrict__ act,
    const float* __restrict__ scale, const float* __restrict__ shift,
    float* __restrict__ pooled, int stageoff) {
  __shared__ ushort tile[4][32][72];
  __shared__ float pool[64];
  const int tid = threadIdx.x, lane = tid & 63, w = tid >> 6;
  const int q = lane & 31, h = lane >> 5;
  const int nbase = blockIdx.x * 128 + w * 32;
  const int node = nbase + q;
  const int g = blockIdx.x >> 3;
  if (tid < 64) pool[tid] = 0.f;
  __syncthreads();

  const int* np = nbr + (size_t)node * 6;
  const int j0 = np[0], j1 = np[1], j2 = np[2], j3 = np[3], j4 = np[4], j5 = np[5];

  // issue ALL 24 gather loads first (independent -> ILP hides L2 latency)
  f16x8 L[6][4];
  {
    const ushort* b0 = hIn + (size_t)j0 * 64 + 8 * h;
    const ushort* b1_ = hIn + (size_t)j1 * 64 + 8 * h;
    const ushort* b2_ = hIn + (size_t)j2 * 64 + 8 * h;
    const ushort* b3 = hIn + (size_t)j3 * 64 + 8 * h;
    const ushort* b4 = hIn + (size_t)j4 * 64 + 8 * h;
    const ushort* b5 = hIn + (size_t)j5 * 64 + 8 * h;
#pragma unroll
    for (int ks = 0; ks < 4; ++ks) {
      L[0][ks] = *(const f16x8*)(b0 + 16 * ks);
      L[1][ks] = *(const f16x8*)(b1_ + 16 * ks);
      L[2][ks] = *(const f16x8*)(b2_ + 16 * ks);
      L[3][ks] = *(const f16x8*)(b3 + 16 * ks);
      L[4][ks] = *(const f16x8*)(b4 + 16 * ks);
      L[5][ks] = *(const f16x8*)(b5 + 16 * ks);
    }
  }

  f16x8 Af[4];
#pragma unroll
  for (int ks = 0; ks < 4; ++ks) {
    const int off = 16 * ks + 8 * h;
    float s0=0.f,s1=0.f,s2=0.f,s3=0.f,s4=0.f,s5=0.f,s6=0.f,s7=0.f;
#pragma unroll
    for (int k = 0; k < 6; ++k) {
      f16x8 v = L[k][ks];
      s0 += (float)v[0]; s1 += (float)v[1]; s2 += (float)v[2]; s3 += (float)v[3];
      s4 += (float)v[4]; s5 += (float)v[5]; s6 += (float)v[6]; s7 += (float)v[7];
    }
    if (BN) {
      f4 sa = *(const f4*)(scale + off), sb = *(const f4*)(scale + off + 4);
      f4 ha = *(const f4*)(shift + off), hb = *(const f4*)(shift + off + 4);
      s0 = s0*sa.x + 6.f*ha.x; s1 = s1*sa.y + 6.f*ha.y;
      s2 = s2*sa.z + 6.f*ha.z; s3 = s3*sa.w + 6.f*ha.w;
      s4 = s4*sb.x + 6.f*hb.x; s5 = s5*sb.y + 6.f*hb.y;
      s6 = s6*sb.z + 6.f*hb.z; s7 = s7*sb.w + 6.f*hb.w;
    }
    f16x8 f;
    f[0]=(f16)s0; f[1]=(f16)s1; f[2]=(f16)s2; f[3]=(f16)s3;
    f[4]=(f16)s4; f[5]=(f16)s5; f[6]=(f16)s6; f[7]=(f16)s7;
    Af[ks] = f;
  }

  f32x16 c0 = Z16, c1 = Z16;
#pragma unroll
  for (int ks = 0; ks < 4; ++ks) {
    f16x8 B0 = *(const f16x8*)(wt + q * 64 + 16 * ks + 8 * h);
    f16x8 B1 = *(const f16x8*)(wt + (q + 32) * 64 + 16 * ks + 8 * h);
    c0 = __builtin_amdgcn_mfma_f32_32x32x16_f16(Af[ks], B0, c0, 0, 0, 0);
    c1 = __builtin_amdgcn_mfma_f32_32x32x16_f16(Af[ks], B1, c1, 0, 0, 0);
  }
  {
    const float bb0 = 6.f * bias[q], bb1 = 6.f * bias[q + 32];
#pragma unroll
    for (int r = 0; r < 16; ++r) {
      const int nd = (r & 3) + 8 * (r >> 2) + 4 * h;
      tile[w][nd][q] = f2h_u(c0[r] + bb0);
      tile[w][nd][q + 32] = f2h_u(c1[r] + bb1);
    }
  }

  const int a = lane >> 3, b = lane & 7;
  f4 aa0 = *(const f4*)(act + 8 * b), aa1 = *(const f4*)(act + 8 * b + 4);
  f4 rs0, rs1, rh0, rh1;
  if (BN) {
    rs0 = *(const f4*)(scale + 8 * b); rs1 = *(const f4*)(scale + 8 * b + 4);
    rh0 = *(const f4*)(shift + 8 * b); rh1 = *(const f4*)(shift + 8 * b + 4);
  }
  f4 ps0 = {0.f,0.f,0.f,0.f}, ps1 = ps0;
#pragma unroll
  for (int r = 0; r < 4; ++r) {
    const int nd = 4 * a + r;
    const size_t gn = (size_t)(nbase + nd) * 64 + 8 * b;
    f16x8 z = *(const f16x8*)&tile[w][nd][8 * b];
    f16x8 ro = *(const f16x8*)(hIn + gn);
    float v0 = (float)z[0] + (BN ? rs0.x * (float)ro[0] + rh0.x : (float)ro[0]);
    float v1 = (float)z[1] + (BN ? rs0.y * (float)ro[1] + rh0.y : (float)ro[1]);
    float v2 = (float)z[2] + (BN ? rs0.z * (float)ro[2] + rh0.z : (float)ro[2]);
    float v3 = (float)z[3] + (BN ? rs0.w * (float)ro[3] + rh0.w : (float)ro[3]);
    float v4 = (float)z[4] + (BN ? rs1.x * (float)ro[4] + rh1.x : (float)ro[4]);
    float v5 = (float)z[5] + (BN ? rs1.y * (float)ro[5] + rh1.y : (float)ro[5]);
    float v6 = (float)z[6] + (BN ? rs1.z * (float)ro[6] + rh1.z : (float)ro[6]);
    float v7 = (float)z[7] + (BN ? rs1.w * (float)ro[7] + rh1.w : (float)ro[7]);
    v0 = v0 >= 0.f ? v0 : aa0.x * v0;  v1 = v1 >= 0.f ? v1 : aa0.y * v1;
    v2 = v2 >= 0.f ? v2 : aa0.z * v2;  v3 = v3 >= 0.f ? v3 : aa0.w * v3;
    v4 = v4 >= 0.f ? v4 : aa1.x * v4;  v5 = v5 >= 0.f ? v5 : aa1.y * v5;
    v6 = v6 >= 0.f ? v6 : aa1.z * v6;  v7 = v7 >= 0.f ? v7 : aa1.w * v7;
    ps0.x += v0; ps0.y += v1; ps0.z += v2; ps0.w += v3;
    ps1.x += v4; ps1.y += v5; ps1.z += v6; ps1.w += v7;
    f16x8 o;
    o[0]=(f16)v0; o[1]=(f16)v1; o[2]=(f16)v2; o[3]=(f16)v3;
    o[4]=(f16)v4; o[5]=(f16)v5; o[6]=(f16)v6; o[7]=(f16)v7;
    *(f16x8*)(hOut + gn) = o;
  }
#pragma unroll
  for (int m = 8; m <= 32; m <<= 1) {
    ps0.x += __shfl_xor(ps0.x, m, 64); ps0.y += __shfl_xor(ps0.y, m, 64);
    ps0.z += __shfl_xor(ps0.z, m, 64); ps0.w += __shfl_xor(ps0.w, m, 64);
    ps1.x += __shfl_xor(ps1.x, m, 64); ps1.y += __shfl_xor(ps1.y, m, 64);
    ps1.z += __shfl_xor(ps1.z, m, 64); ps1.w += __shfl_xor(ps1.w, m, 64);
  }
  if (a == 0) {
    atomicAdd(&pool[8 * b + 0], ps0.x); atomicAdd(&pool[8 * b + 1], ps0.y);
    atomicAdd(&pool[8 * b + 2], ps0.z); atomicAdd(&pool[8 * b + 3], ps0.w);
    atomicAdd(&pool[8 * b + 4], ps1.x); atomicAdd(&pool[8 * b + 5], ps1.y);
    atomicAdd(&pool[8 * b + 6], ps1.z); atomicAdd(&pool[8 * b + 7], ps1.w);
  }
  __syncthreads();
  if (tid < 64) atomicAdd(&pooled[g * 320 + stageoff + tid], pool[tid]);
}

// ---------------- FFN head: one block per graph ----------------------------
__global__ __launch_bounds__(256) void kffn(const float* __restrict__ pooled,
    const float* __restrict__ W1, const float* __restrict__ b1,
    const float* __restrict__ W2, const float* __restrict__ b2,
    float* __restrict__ out) {
  __shared__ float pg[320];
  __shared__ float z1[320];
  __shared__ float red[4];
  const int g = blockIdx.x, tid = threadIdx.x;
  for (int i = tid; i < 320; i += 256) pg[i] = pooled[g * 320 + i];
  __syncthreads();
  for (int o = tid; o < 320; o += 256) {
    float acc = b1[o];
    for (int d = 0; d < 320; ++d) acc += pg[d] * W1[d * 320 + o];
    z1[o] = acc >= 0.f ? acc : 0.01f * acc;
  }
  __syncthreads();
  float p = 0.f;
  for (int o = tid; o < 320; o += 256) p += z1[o] * W2[o];
#pragma unroll
  for (int m = 32; m; m >>= 1) p += __shfl_xor(p, m, 64);
  if ((tid & 63) == 0) red[tid >> 6] = p;
  __syncthreads();
  if (tid == 0) out[g] = red[0] + red[1] + red[2] + red[3] + b2[0];
}

extern "C" void kernel_launch(void* const* d_in, const int* in_sizes, int n_in,
                              void* d_out, int out_size, void* d_ws, size_t ws_size,
                              hipStream_t stream) {
  const float* x        = (const float*)d_in[0];
  const float* pre_W1   = (const float*)d_in[2];
  const float* pre_b1   = (const float*)d_in[3];
  const float* pre_a1   = (const float*)d_in[4];
  const float* pre_W2   = (const float*)d_in[5];
  const float* pre_b2   = (const float*)d_in[6];
  const float* pre_a2   = (const float*)d_in[7];
  const float* bn_gamma = (const float*)d_in[8];
  const float* bn_beta  = (const float*)d_in[9];
  const float* act_a    = (const float*)d_in[10];
  const float* conv_W   = (const float*)d_in[11];
  const float* conv_b   = (const float*)d_in[12];
  const float* ffn_W1   = (const float*)d_in[13];
  const float* ffn_b1   = (const float*)d_in[14];
  const float* ffn_W2   = (const float*)d_in[15];
  const float* ffn_b2   = (const float*)d_in[16];
  float* out = (float*)d_out;

  ushort* hA16 = (ushort*)d_ws;                     // N*64 f16 (8 MB)
  ushort* hB16 = hA16 + 4194304;                    // N*64 f16 (8 MB)
  ushort* xf16 = hB16 + 4194304;                    // N*64 f16 (8 MB)
  uint*   sq2  = (uint*)(xf16 + 4194304);           // N
  int*    nbr  = (int*)(sq2 + 65536);               // N*6
  ushort* wt   = (ushort*)(nbr + 393216);           // 6*4096 f16 (48 KB)
  float* stats = (float*)(wt + 24576);
  float* gsq    = stats;                            // 64
  float* gsumg  = stats + 64;                       // 64*64
  float* scale  = stats + 64 + 4096;                // 64
  float* shift  = stats + 64 + 4096 + 64;           // 64
  float* pooled = stats + 64 + 4096 + 128;          // 64*320

  hipMemsetAsync(stats, 0, (64 + 4096 + 128 + 64 * 320) * sizeof(float), stream);

  kwprep<<<6, 256, 0, stream>>>(pre_W1, pre_W2, conv_W, wt);
  kpre  <<<512, 256, 0, stream>>>(x, wt, pre_b1, pre_a1, wt + 4096, pre_b2, pre_a2,
                                  hA16, gsumg, gsq, xf16, sq2);
  kknn  <<<2048, 256, 0, stream>>>(xf16, sq2, nbr);
  kfin  <<<64, 64, 0, stream>>>(gsumg, gsq, bn_gamma, bn_beta, scale, shift, pooled);
  kconv<1><<<512, 256, 0, stream>>>(hA16, hB16, nbr, wt + 2*4096, conv_b,       act_a, scale, shift, pooled, 64);
  kconv<0><<<512, 256, 0, stream>>>(hB16, hA16, nbr, wt + 3*4096, conv_b + 64,  act_a, scale, shift, pooled, 128);
  kconv<0><<<512, 256, 0, stream>>>(hA16, hB16, nbr, wt + 4*4096, conv_b + 128, act_a, scale, shift, pooled, 192);
  kconv<0><<<512, 256, 0, stream>>>(hB16, hA16, nbr, wt + 5*4096, conv_b + 192, act_a, scale, shift, pooled, 256);
  kffn  <<<64, 256, 0, stream>>>(pooled, ffn_W1, ffn_b1, ffn_W2, ffn_b2, out);
}